// Round 12
// baseline (466.884 us; speedup 1.0000x reference)
//
#include <hip/hip_runtime.h>
#include <hip/hip_bf16.h>
#include <stdint.h>

// Problem constants (fixed by setup_inputs)
#define Bn 64
#define Sn 2048
#define Dn 768
#define An 256
#define EPSF 1e-7f
#define ROWS 32              // s-rows per chunk
#define NCHUNK (Sn / ROWS)   // 64 chunks per batch
#define NK (Dn / 32)         // 24 K-steps of 32
#define CPB 8                // chunks per block
#define NBLK ((Bn * NCHUNK) / CPB)   // 512 blocks = 2 per CU

typedef __bf16 bf16x8 __attribute__((ext_vector_type(8)));
typedef float f32x4 __attribute__((ext_vector_type(4)));

// ---------------- pack W (fp32 row-major DxA) -> bf16 MFMA-B-fragment layout ----
// packed[( (kk*16 + cb)*64 + lane )*8 + e] = bf16( W[kk*32 + (lane>>4)*8 + e][cb*16 + (lane&15)] )
__global__ void pack_w_kernel(const float* __restrict__ W, unsigned short* __restrict__ pw) {
  int kk = blockIdx.x >> 4;     // 0..23
  int cb = blockIdx.x & 15;     // 0..15
  int l  = threadIdx.x;         // 0..63
  int a  = cb * 16 + (l & 15);
  int k0 = kk * 32 + (l >> 4) * 8;
  bf16x8 pk;
#pragma unroll
  for (int j = 0; j < 8; ++j) pk[j] = (__bf16)W[(k0 + j) * An + a];
  *(bf16x8*)(pw + ((size_t)((kk * 16 + cb) * 64 + l)) * 8) = pk;
}

// ---------------- main: persistent blocks + cross-chunk prefetch ----------------
// 512 blocks (2/CU), 256 threads = 4 waves, CPB=8 chunks each.
// Per iteration: wf-prologue -> K-loop (W-only vmcnt FIFO, depth-4 rotation)
// -> batch-issue next chunk's x loads (sched_barrier-pinned; in flight across
// the raw-barrier epilogue/pool phases) -> cvt+write xs (progressive BW-paced
// x wait). vmcnt is never drained at a barrier inside the loop.
__launch_bounds__(256, 2)
__global__ void attn_pool_main(const float* __restrict__ x,
                               const unsigned short* __restrict__ pw,
                               const float* __restrict__ bias,
                               const float* __restrict__ u,
                               const int* __restrict__ mask,
                               float* __restrict__ outpart,
                               float* __restrict__ sumpart) {
  __shared__ __align__(16) char xs[49152];   // 32 rows x 768 bf16, XOR-swizzled
  __shared__ float aitp[128];
  __shared__ float aitv[32];
  __shared__ float outred[1536];

  const int tid  = threadIdx.x;
  const int lane = tid & 63;
  const int w    = tid >> 6;      // wave 0..3, cols w*64..w*64+63
  const int cid0 = blockIdx.x * CPB;
  const int b    = cid0 >> 6;     // constant per block (CPB divides 64)

  const float* xb0 = x + (size_t)b * Sn * Dn;

  const int arow  = lane & 15;
  const int kh16  = (lane >> 4) * 16;
  const int swz   = (arow & 7) << 4;
  const char* wlane = (const char*)pw + (size_t)(w * 4) * 1024 + (size_t)lane * 16;

  float4 ldA[12], ldB[12];

  // ---- prologue: batch-issue + cvt chunk cid0 ----
  {
    const float* xb = xb0 + (size_t)(cid0 & 63) * ROWS * Dn;
#pragma unroll
    for (int j = 0; j < 12; ++j) {
      int unit = tid + j * 256;
      int row  = unit / 96;
      int ku   = unit % 96;
      const float4* g = (const float4*)(xb + (size_t)row * Dn + ku * 8);
      ldA[j] = g[0];
      ldB[j] = g[1];
    }
    __builtin_amdgcn_sched_barrier(0);
#pragma unroll
    for (int j = 0; j < 12; ++j) {
      int unit = tid + j * 256;
      int row  = unit / 96;
      int ku   = unit % 96;
      bf16x8 pk;
      pk[0] = (__bf16)ldA[j].x; pk[1] = (__bf16)ldA[j].y;
      pk[2] = (__bf16)ldA[j].z; pk[3] = (__bf16)ldA[j].w;
      pk[4] = (__bf16)ldB[j].x; pk[5] = (__bf16)ldB[j].y;
      pk[6] = (__bf16)ldB[j].z; pk[7] = (__bf16)ldB[j].w;
      int off = (row * 1536 + ku * 16) ^ ((row & 7) << 4);
      *(bf16x8*)(xs + off) = pk;
    }
  }

  for (int i = 0; i < CPB; ++i) {
    const int cid = cid0 + i;
    const int s0  = (cid & 63) * ROWS;

    float mval = 0.f;
    if (tid < 32) mval = (float)mask[(size_t)b * Sn + s0 + tid];

    asm volatile("s_waitcnt lgkmcnt(0)" ::: "memory");
    __builtin_amdgcn_s_barrier();     // xs published

    // ---- wf prologue: kk=0..3 (issued before any x loads this iter) ----
    bf16x8 wf[4][4];
#pragma unroll
    for (int s = 0; s < 4; ++s) {
      const char* wk = wlane + (size_t)s * 16384;
      wf[s][0] = *(const bf16x8*)(wk);
      wf[s][1] = *(const bf16x8*)(wk + 1024);
      wf[s][2] = *(const bf16x8*)(wk + 2048);
      wf[s][3] = *(const bf16x8*)(wk + 3072);
    }

    f32x4 acc[2][4];
#pragma unroll
    for (int p = 0; p < 2; ++p)
#pragma unroll
      for (int q = 0; q < 4; ++q) acc[p][q] = (f32x4){0.f, 0.f, 0.f, 0.f};

    // ---- K-loop: clean W-only vmcnt FIFO, depth-4 rotation ----
#pragma unroll
    for (int kk = 0; kk < NK; ++kk) {
      const int s = kk & 3;
      bf16x8 a0 = *(const bf16x8*)(xs + ((arow * 1536 + kk * 64 + kh16) ^ swz));
      bf16x8 a1 = *(const bf16x8*)(xs + (((arow + 16) * 1536 + kk * 64 + kh16) ^ swz));
      bf16x8 b0 = wf[s][0], b1 = wf[s][1], b2 = wf[s][2], b3 = wf[s][3];
      if (kk + 4 < NK) {
        const char* wk = wlane + (size_t)(kk + 4) * 16384;
        wf[s][0] = *(const bf16x8*)(wk);
        wf[s][1] = *(const bf16x8*)(wk + 1024);
        wf[s][2] = *(const bf16x8*)(wk + 2048);
        wf[s][3] = *(const bf16x8*)(wk + 3072);
      }
      acc[0][0] = __builtin_amdgcn_mfma_f32_16x16x32_bf16(a0, b0, acc[0][0], 0, 0, 0);
      acc[1][0] = __builtin_amdgcn_mfma_f32_16x16x32_bf16(a1, b0, acc[1][0], 0, 0, 0);
      acc[0][1] = __builtin_amdgcn_mfma_f32_16x16x32_bf16(a0, b1, acc[0][1], 0, 0, 0);
      acc[1][1] = __builtin_amdgcn_mfma_f32_16x16x32_bf16(a1, b1, acc[1][1], 0, 0, 0);
      acc[0][2] = __builtin_amdgcn_mfma_f32_16x16x32_bf16(a0, b2, acc[0][2], 0, 0, 0);
      acc[1][2] = __builtin_amdgcn_mfma_f32_16x16x32_bf16(a1, b2, acc[1][2], 0, 0, 0);
      acc[0][3] = __builtin_amdgcn_mfma_f32_16x16x32_bf16(a0, b3, acc[0][3], 0, 0, 0);
      acc[1][3] = __builtin_amdgcn_mfma_f32_16x16x32_bf16(a1, b3, acc[1][3], 0, 0, 0);
    }
    __builtin_amdgcn_sched_barrier(0);

    // ---- batch-issue next chunk's x loads (fly across epilogue/pool) ----
    if (i + 1 < CPB) {
      const float* xb = xb0 + (size_t)((cid + 1) & 63) * ROWS * Dn;
#pragma unroll
      for (int j = 0; j < 12; ++j) {
        int unit = tid + j * 256;
        int row  = unit / 96;
        int ku   = unit % 96;
        const float4* g = (const float4*)(xb + (size_t)row * Dn + ku * 8);
        ldA[j] = g[0];
        ldB[j] = g[1];
      }
      __builtin_amdgcn_sched_barrier(0);
    }

    // ---- epilogue: tanh + dot with u -> per-row partials ----
    float rowp[8];
#pragma unroll
    for (int p = 0; p < 8; ++p) rowp[p] = 0.f;
#pragma unroll
    for (int cbi = 0; cbi < 4; ++cbi) {
      int col = w * 64 + cbi * 16 + arow;
      float bia = bias[col];
      float uv  = u[col];
#pragma unroll
      for (int rb = 0; rb < 2; ++rb) {
#pragma unroll
        for (int r = 0; r < 4; ++r) {
          float v = acc[rb][cbi][r] + bia;
          v = fminf(fmaxf(v, -15.f), 15.f);
          float e2 = __expf(2.f * v);
          float th = (e2 - 1.f) * __builtin_amdgcn_rcpf(e2 + 1.f);
          rowp[rb * 4 + r] += th * uv;
        }
      }
    }
#pragma unroll
    for (int m = 1; m < 16; m <<= 1)
#pragma unroll
      for (int p = 0; p < 8; ++p) rowp[p] += __shfl_xor(rowp[p], m, 64);

    if (arow == 0) {
      int rbase = (lane >> 4) * 4;
#pragma unroll
      for (int rb = 0; rb < 2; ++rb)
#pragma unroll
        for (int r = 0; r < 4; ++r)
          aitp[w * 32 + rb * 16 + rbase + r] = rowp[rb * 4 + r];
    }
    asm volatile("s_waitcnt lgkmcnt(0)" ::: "memory");
    __builtin_amdgcn_s_barrier();     // aitp ready (x stream stays in flight)

    if (tid < 32) {
      float s = aitp[tid] + aitp[32 + tid] + aitp[64 + tid] + aitp[96 + tid];
      float av = __expf(s) * mval;
      aitv[tid] = av;
      float t = av;
#pragma unroll
      for (int m = 1; m < 32; m <<= 1) t += __shfl_xor(t, m, 64);
      if (tid == 0) sumpart[cid] = t;
    }
    asm volatile("s_waitcnt lgkmcnt(0)" ::: "memory");
    __builtin_amdgcn_s_barrier();     // aitv ready

    // ---- pooling: 192 threads, 2 row-groups of 16 rows ----
    {
      float pac[8];
#pragma unroll
      for (int e = 0; e < 8; ++e) pac[e] = 0.f;
      int rg = tid / 96;              // 0..1 for tid<192
      int du = tid % 96;              // 8-d unit
      if (tid < 192) {
#pragma unroll
        for (int rr = 0; rr < 16; ++rr) {
          int row = rg * 16 + rr;
          int off = (row * 1536 + du * 16) ^ ((row & 7) << 4);
          bf16x8 xv = *(const bf16x8*)(xs + off);
          float a = aitv[row];
#pragma unroll
          for (int e = 0; e < 8; ++e) pac[e] += a * (float)xv[e];
        }
#pragma unroll
        for (int e = 0; e < 8; ++e) outred[rg * 768 + du * 8 + e] = pac[e];
      }
    }
    asm volatile("s_waitcnt lgkmcnt(0)" ::: "memory");
    __builtin_amdgcn_s_barrier();     // outred ready; all xs reads done

    {
      float* op = outpart + (size_t)cid * Dn;
#pragma unroll
      for (int j = 0; j < 3; ++j) {
        int d = tid + j * 256;
        op[d] = outred[d] + outred[768 + d];
      }
    }

    // ---- cvt next chunk -> xs (the only x vmcnt wait; progressive, BW-paced) ----
    if (i + 1 < CPB) {
#pragma unroll
      for (int j = 0; j < 12; ++j) {
        int unit = tid + j * 256;
        int row  = unit / 96;
        int ku   = unit % 96;
        bf16x8 pk;
        pk[0] = (__bf16)ldA[j].x; pk[1] = (__bf16)ldA[j].y;
        pk[2] = (__bf16)ldA[j].z; pk[3] = (__bf16)ldA[j].w;
        pk[4] = (__bf16)ldB[j].x; pk[5] = (__bf16)ldB[j].y;
        pk[6] = (__bf16)ldB[j].z; pk[7] = (__bf16)ldB[j].w;
        int off = (row * 1536 + ku * 16) ^ ((row & 7) << 4);
        *(bf16x8*)(xs + off) = pk;
      }
    }
  }
}

// ---------------- finalize: out[b,d] = sum_c outpart / (sum_c sumpart + eps) ----
// grid = 64 b x 3 slabs of 256 d
__global__ void finalize_kernel(const float* __restrict__ outpart,
                                const float* __restrict__ sumpart,
                                float* __restrict__ out) {
  __shared__ float sh;
  int b = blockIdx.x / 3, slab = blockIdx.x % 3;
  int tid = threadIdx.x;
  if (tid < 64) {
    float v = sumpart[b * 64 + tid];
#pragma unroll
    for (int m = 1; m < 64; m <<= 1) v += __shfl_xor(v, m, 64);
    if (tid == 0) sh = v + EPSF;
  }
  __syncthreads();
  float inv = 1.0f / sh;
  int d = slab * 256 + tid;
  const float* p = outpart + (size_t)b * 64 * Dn + d;
  float s = 0.f;
#pragma unroll 8
  for (int c = 0; c < 64; ++c) s += p[(size_t)c * Dn];
  out[b * Dn + d] = s * inv;
}

extern "C" void kernel_launch(void* const* d_in, const int* in_sizes, int n_in,
                              void* d_out, int out_size, void* d_ws, size_t ws_size,
                              hipStream_t stream) {
  const float* x    = (const float*)d_in[0];
  const float* W    = (const float*)d_in[1];
  const float* bias = (const float*)d_in[2];
  const float* u    = (const float*)d_in[3];
  const int*   mask = (const int*)d_in[4];
  float* out = (float*)d_out;

  unsigned short* pw = (unsigned short*)d_ws;                      // 393216 B
  float* outpart = (float*)((char*)d_ws + 393216);                 // 64*64*768*4 = 12.58 MB
  float* sumpart = (float*)((char*)d_ws + 393216 + 12582912);      // 16 KB

  hipLaunchKernelGGL(pack_w_kernel, dim3(24 * 16), dim3(64), 0, stream, W, pw);
  hipLaunchKernelGGL(attn_pool_main, dim3(NBLK), dim3(256), 0, stream,
                     x, pw, bias, u, mask, outpart, sumpart);
  hipLaunchKernelGGL(finalize_kernel, dim3(Bn * 3), dim3(256), 0, stream,
                     outpart, sumpart, out);
}